// Round 2
// 523.368 us; speedup vs baseline: 1.0463x; 1.0463x over previous
//
#include <hip/hip_runtime.h>

// Unfold (im2col): IN (4,64,224,224) f32, K=3x3, pad=1, stride=1, dil=1
// (reference nh=k+dil quirk -> output spatial 223x223)
// out[ch][pos], ch=(b*64+c)*9+i*3+j (2304 channels), pos=oh*223+ow (49729)
//   = x[b,c,oh+i-1,ow+j-1] (zero-padded)
//
// V2b: channel-uniform blocks (q,i,j scalar), one magic-div per float4,
// 4 independent float4 groups per thread (ILP, no serial carry chain),
// nontemporal stores (native ext_vector float4 — HIP float4 struct is
// rejected by __builtin_nontemporal_store) so the 458MB output stream
// doesn't evict the 51MB input (reused 9x) from L2.

#define OW       223u
#define OSP      49729u      // 223*223
#define PLANE_IN 50176u      // 224*224
#define NCH      2304u       // 4*64*9

typedef float vfloat4 __attribute__((ext_vector_type(4)));

__global__ __launch_bounds__(256) void unfold223_v2(
    const float* __restrict__ x, float* __restrict__ out)
{
    const unsigned ch = blockIdx.y;            // (b*64+c)*9 + i*3 + j  (uniform)
    const unsigned q  = ch / 9u;               // SALU
    const unsigned r  = ch - q * 9u;
    const int im1 = (int)(r / 3u) - 1;         // i-1  (uniform)
    const int jm1 = (int)(r % 3u) - 1;         // j-1  (uniform)
    const float* __restrict__ xq = x + q * PLANE_IN;
    float* __restrict__ och = out + (unsigned long long)ch * OSP;

    // OSP % 4 == 1, so channel base alignment rotates: first 16B-aligned elem
    const unsigned a  = (4u - (ch & 3u)) & 3u;
    const unsigned nv = (OSP - a) >> 2;        // aligned float4 count (12431/12432)

    const unsigned tid = threadIdx.x;

    // head [0,a) + tail [a+4nv, OSP): <=5 scalar elems per channel, block x==0
    if (blockIdx.x == 0u && tid < 8u) {
        const unsigned nhead = a;
        const unsigned ntail = OSP - a - 4u * nv;
        if (tid < nhead + ntail) {
            unsigned pos = (tid < nhead) ? tid : (a + 4u * nv + (tid - nhead));
            unsigned oh = pos / OW;
            unsigned ow = pos - oh * OW;
            int ih = (int)oh + im1;
            int iw = (int)ow + jm1;
            bool valid = ((unsigned)ih < 224u) && ((unsigned)iw < 224u);
            unsigned idx = valid ? ((unsigned)ih * 224u + (unsigned)iw) : 0u;
            float val = xq[idx];
            och[pos] = valid ? val : 0.0f;
        }
    }

    // main: 4 float4 per thread, block-strided (independent groups -> ILP)
    const unsigned vbase = blockIdx.x * 1024u + tid;
#pragma unroll
    for (int k = 0; k < 4; ++k) {
        const unsigned v = vbase + (unsigned)(k * 256);
        if (v < nv) {
            const unsigned pos = a + v * 4u;       // 16B-aligned within out
            const unsigned oh0 = pos / OW;         // single magic-mul divide
            const unsigned ow0 = pos - oh0 * OW;
            float vals[4];
#pragma unroll
            for (int e = 0; e < 4; ++e) {
                unsigned ow = ow0 + (unsigned)e;
                unsigned oh = oh0;
                if (ow >= OW) { ow -= OW; oh += 1u; }   // cheap, chain-free
                int ih = (int)oh + im1;
                int iw = (int)ow + jm1;
                bool valid = ((unsigned)ih < 224u) && ((unsigned)iw < 224u);
                unsigned idx = valid ? ((unsigned)ih * 224u + (unsigned)iw) : 0u;
                float val = xq[idx];
                vals[e] = valid ? val : 0.0f;
            }
            vfloat4 f4 = { vals[0], vals[1], vals[2], vals[3] };
            __builtin_nontemporal_store(f4, reinterpret_cast<vfloat4*>(och + pos));
        }
    }
}

extern "C" void kernel_launch(void* const* d_in, const int* in_sizes, int n_in,
                              void* d_out, int out_size, void* d_ws, size_t ws_size,
                              hipStream_t stream)
{
    const float* x = (const float*)d_in[0];
    float* out = (float*)d_out;
    // max nv = 12432 -> ceil(12432/1024) = 13 blocks in x
    unfold223_v2<<<dim3(13, NCH), dim3(256), 0, stream>>>(x, out);
}